// Round 3
// baseline (602.278 us; speedup 1.0000x reference)
//
#include <hip/hip_runtime.h>
#include <hip/hip_bf16.h>

// FutureTrajDecoder: 3-layer GRU rollout, B=16384, ES=HS=64, T=128, NOUT=2.
// Persistent kernel: 512 WGs x 256 threads; each WG owns BM=32 batch rows for
// all 128 steps. Weights held in per-wave VGPR B-fragments (each wave owns a
// 16-col triple of the hidden dim). INPUTS FP32, OUTPUT FP32 (round-2 bf16
// store was the bug: error signature decoded as half-filled fp32 buffer).
// Activations staged fp16 in LDS; h-state fp32 in registers (C-layout) so
// the z*(h-n) carry never rounds. MFMA 16x16x32 f16, fp32 accumulate.

#define ESZ   64
#define HSZ   64
#define NLAY  3
#define TLEN  128
#define NOUTC 2
#define BM    32
#define LDW   72            // padded LDS row stride (fp16 elems): 144B, 16B-aligned
#define HB    (BM*LDW)

typedef _Float16 half8 __attribute__((ext_vector_type(8)));
typedef float    floatx4 __attribute__((ext_vector_type(4)));

__device__ __forceinline__ float sigm(float x) {
    return __builtin_amdgcn_rcpf(1.f + __builtin_amdgcn_exp2f(-1.44269504f * x));
}
__device__ __forceinline__ float tanh_(float x) {
    return 1.f - 2.f * __builtin_amdgcn_rcpf(1.f + __builtin_amdgcn_exp2f(2.88539008f * x));
}

#define MFMA(a, b, c) __builtin_amdgcn_mfma_f32_16x16x32_f16((a), (b), (c), 0, 0, 0)

__global__ __launch_bounds__(256, 2) void gru_rollout(
    const float* __restrict__ enc,     // (B, 64) fp32
    const float* __restrict__ emb_w,   // (64, 64)
    const float* __restrict__ emb_b,   // (64,)
    const float* __restrict__ w_ih,    // (3, 192, 64)
    const float* __restrict__ w_hh,    // (3, 192, 64)
    const float* __restrict__ b_ih,    // (3, 192)
    const float* __restrict__ b_hh,    // (3, 192)
    const float* __restrict__ out_w,   // (2, 64)
    const float* __restrict__ out_b,   // (2,)
    float* __restrict__ out)           // (B, 128, 2) fp32
{
    __shared__ _Float16 s_inp[HB];              // embedding output
    __shared__ _Float16 s_h[NLAY * 2 * HB];     // double-buffered hidden per layer
    __shared__ _Float16 s_ow[2 * LDW];          // out_w staged

    const int tid  = threadIdx.x;
    const int wave = tid >> 6, lane = tid & 63;
    const int q = lane >> 4, c = lane & 15;     // quad / col-within-tile
    const int u = (wave << 4) | c;              // owned hidden column 0..63
    const long wgbase = (long)blockIdx.x * BM;

    // ---- stage initial x/h (= enc) into all 3 layer buffers, parity 0 ----
    {
        const int r = tid >> 3, k0 = (tid & 7) << 3;   // 8 floats per thread
        const float* p = enc + (wgbase + r) * ESZ + k0;
        floatx4 s0 = *(const floatx4*)p;
        floatx4 s1 = *(const floatx4*)(p + 4);
        half8 v;
        #pragma unroll
        for (int j = 0; j < 4; ++j) { v[j] = (_Float16)s0[j]; v[4 + j] = (_Float16)s1[j]; }
        *(half8*)&s_h[0 * 2 * HB + r * LDW + k0] = v;
        *(half8*)&s_h[1 * 2 * HB + r * LDW + k0] = v;
        *(half8*)&s_h[2 * 2 * HB + r * LDW + k0] = v;
    }
    if (tid < NOUTC * HSZ) {
        const int n = tid >> 6, k = tid & 63;
        s_ow[n * LDW + k] = (_Float16)out_w[n * HSZ + k];
    }

    // ---- persistent weight B-fragments (B[k][n] = W[n][k]; n-within-tile = lane&15) ----
    auto ldw8 = [&](const float* p) {
        floatx4 s0 = *(const floatx4*)p;
        floatx4 s1 = *(const floatx4*)(p + 4);
        half8 v;
        #pragma unroll
        for (int j = 0; j < 4; ++j) { v[j] = (_Float16)s0[j]; v[4 + j] = (_Float16)s1[j]; }
        return v;
    };
    half8 bfE[2], bfR[NLAY][4], bfZ[NLAY][4], bfNi[NLAY][2], bfNh[NLAY][2];
    #pragma unroll
    for (int ks = 0; ks < 2; ++ks)
        bfE[ks] = ldw8(emb_w + u * ESZ + ks * 32 + q * 8);
    #pragma unroll
    for (int l = 0; l < NLAY; ++l) {
        const float* wi = w_ih + l * 3 * HSZ * ESZ;
        const float* wh = w_hh + l * 3 * HSZ * ESZ;
        #pragma unroll
        for (int ks = 0; ks < 2; ++ks) {
            const int k0 = ks * 32 + q * 8;
            bfR[l][ks]     = ldw8(wi + (u) * ESZ + k0);        // r gate, W_ih rows [0,64)
            bfR[l][2 + ks] = ldw8(wh + (u) * ESZ + k0);        //         W_hh part
            bfZ[l][ks]     = ldw8(wi + (64 + u) * ESZ + k0);   // z gate
            bfZ[l][2 + ks] = ldw8(wh + (64 + u) * ESZ + k0);
            bfNi[l][ks]    = ldw8(wi + (128 + u) * ESZ + k0);  // n gate (input part)
            bfNh[l][ks]    = ldw8(wh + (128 + u) * ESZ + k0);  // n gate (hidden part)
        }
    }
    // biases (per-lane scalar for owned column u)
    const float embb = emb_b[u];
    float brzr[NLAY], brzz[NLAY], bni[NLAY], bnh[NLAY];
    #pragma unroll
    for (int l = 0; l < NLAY; ++l) {
        const int b0 = l * 3 * HSZ;
        brzr[l] = b_ih[b0 + u] + b_hh[b0 + u];
        brzz[l] = b_ih[b0 + 64 + u] + b_hh[b0 + 64 + u];
        bni[l]  = b_ih[b0 + 128 + u];
        bnh[l]  = b_hh[b0 + 128 + u];
    }
    const float outb = (c < NOUTC) ? out_b[c] : 0.f;

    // fp32 h-state in registers, C-layout: row = mt*16 + q*4 + i, col = u
    float hreg[NLAY][2][4];
    #pragma unroll
    for (int mt = 0; mt < 2; ++mt)
        #pragma unroll
        for (int i = 0; i < 4; ++i) {
            const float v = enc[(wgbase + mt * 16 + q * 4 + i) * ESZ + u];
            hreg[0][mt][i] = v; hreg[1][mt][i] = v; hreg[2][mt][i] = v;
        }

    __syncthreads();

    for (int t = 0; t < TLEN; ++t) {
        const int rp = t & 1, wp = rp ^ 1;

        // ---- embedding: inp = x @ emb_w.T + emb_b  (x = h3 of prev step) ----
        {
            const _Float16* xb = &s_h[2 * 2 * HB + rp * HB];
            #pragma unroll
            for (int mt = 0; mt < 2; ++mt) {
                const int ar = (mt * 16 + c) * LDW + q * 8;   // A[m=lane&15][k=quad*8+j]
                half8 a0 = *(const half8*)&xb[ar];
                half8 a1 = *(const half8*)&xb[ar + 32];
                floatx4 acc = {0.f, 0.f, 0.f, 0.f};
                acc = MFMA(a0, bfE[0], acc);
                acc = MFMA(a1, bfE[1], acc);
                #pragma unroll
                for (int i = 0; i < 4; ++i)
                    s_inp[(mt * 16 + q * 4 + i) * LDW + u] = (_Float16)(acc[i] + embb);
            }
        }
        __syncthreads();

        // ---- GRU layers ----
        #pragma unroll
        for (int l = 0; l < NLAY; ++l) {
            const _Float16* inb = (l == 0) ? s_inp : &s_h[(l - 1) * 2 * HB + wp * HB];
            const _Float16* hob = &s_h[l * 2 * HB + rp * HB];
            _Float16*       hnb = &s_h[l * 2 * HB + wp * HB];
            #pragma unroll
            for (int mt = 0; mt < 2; ++mt) {
                const int ar = (mt * 16 + c) * LDW + q * 8;
                half8 ax0 = *(const half8*)&inb[ar];
                half8 ax1 = *(const half8*)&inb[ar + 32];
                half8 ah0 = *(const half8*)&hob[ar];
                half8 ah1 = *(const half8*)&hob[ar + 32];
                floatx4 accr = {0,0,0,0}, accz = {0,0,0,0}, accni = {0,0,0,0}, accnh = {0,0,0,0};
                accr = MFMA(ax0, bfR[l][0], accr); accr = MFMA(ax1, bfR[l][1], accr);
                accr = MFMA(ah0, bfR[l][2], accr); accr = MFMA(ah1, bfR[l][3], accr);
                accz = MFMA(ax0, bfZ[l][0], accz); accz = MFMA(ax1, bfZ[l][1], accz);
                accz = MFMA(ah0, bfZ[l][2], accz); accz = MFMA(ah1, bfZ[l][3], accz);
                accni = MFMA(ax0, bfNi[l][0], accni); accni = MFMA(ax1, bfNi[l][1], accni);
                accnh = MFMA(ah0, bfNh[l][0], accnh); accnh = MFMA(ah1, bfNh[l][1], accnh);
                #pragma unroll
                for (int i = 0; i < 4; ++i) {
                    const float r = sigm(accr[i] + brzr[l]);
                    const float z = sigm(accz[i] + brzz[l]);
                    const float n = tanh_(accni[i] + bni[l] + r * (accnh[i] + bnh[l]));
                    const float ho = hreg[l][mt][i];
                    const float hv = n + z * (ho - n);
                    hreg[l][mt][i] = hv;
                    hnb[(mt * 16 + q * 4 + i) * LDW + u] = (_Float16)hv;
                }
            }
            __syncthreads();
        }

        // ---- output projection: out[:, t, :] = h3_new @ out_w.T + out_b ----
        if (wave < 2) {
            const _Float16* h3 = &s_h[2 * 2 * HB + wp * HB];
            const int mt = wave;
            const int ar = (mt * 16 + c) * LDW + q * 8;
            half8 a0 = *(const half8*)&h3[ar];
            half8 a1 = *(const half8*)&h3[ar + 32];
            const int cs = (c < NOUTC) ? c : 1;   // cols >=2 compute garbage, never stored
            half8 b0 = *(const half8*)&s_ow[cs * LDW + q * 8];
            half8 b1 = *(const half8*)&s_ow[cs * LDW + 32 + q * 8];
            floatx4 acc = {0.f, 0.f, 0.f, 0.f};
            acc = MFMA(a0, b0, acc);
            acc = MFMA(a1, b1, acc);
            if (c < NOUTC) {
                #pragma unroll
                for (int i = 0; i < 4; ++i) {
                    const long row = wgbase + mt * 16 + q * 4 + i;
                    out[(row * TLEN + t) * NOUTC + c] = acc[i] + outb;
                }
            }
        }
    }
}

extern "C" void kernel_launch(void* const* d_in, const int* in_sizes, int n_in,
                              void* d_out, int out_size, void* d_ws, size_t ws_size,
                              hipStream_t stream) {
    (void)in_sizes; (void)n_in; (void)d_ws; (void)ws_size; (void)out_size;
    const int grid = 16384 / BM;   // 512 workgroups
    gru_rollout<<<grid, 256, 0, stream>>>(
        (const float*)d_in[0],  // agentFutureTrajEnc
        (const float*)d_in[1],  // emb_w
        (const float*)d_in[2],  // emb_b
        (const float*)d_in[3],  // w_ih
        (const float*)d_in[4],  // w_hh
        (const float*)d_in[5],  // b_ih
        (const float*)d_in[6],  // b_hh
        (const float*)d_in[7],  // out_w
        (const float*)d_in[8],  // out_b
        (float*)d_out);
}

// Round 4
// 517.947 us; speedup vs baseline: 1.1628x; 1.1628x over previous
//
#include <hip/hip_runtime.h>

// FutureTrajDecoder: 3-layer GRU rollout, B=16384, ES=HS=64, T=128, NOUT=2.
// Stage-pipelined persistent kernel: 256 WGs x 1024 threads (16 waves).
// Stages: wave>>2 = {0: emb + out-proj, 1: L0, 2: L1, 3: L2}; wave&3 = column
// group (16 hidden cols each). WG owns 4 batch tiles of 16 rows, skewed one
// barrier-slot apart so all 16 waves work every slot. Each wave holds ONLY
// its stage's weight fragments (~48 VGPRs) -> 4 waves/SIMD occupancy (vs 2
// for the monolithic design whose 152-reg weight set capped occupancy).
// Gate scale constants (-log2e, 2log2e) folded into weights; biases folded
// into MFMA C-init. fp32 h-carry in LDS (col-major float4) so the z*(h-n)
// path never rounds to fp16. Activations fp16 in LDS; MFMA 16x16x32 f16.

#define ESZ   64
#define HSZ   64
#define NLAY  3
#define TLEN  128
#define NOUTC 2
#define TILE  16
#define TILES 4
#define LDW   72              // fp16 row stride (144 B, 16B-aligned)
#define TB    (TILE*LDW)      // one activation tile buffer (fp16 elems)
#define L2E   1.44269504f

typedef _Float16 half8 __attribute__((ext_vector_type(8)));
typedef _Float16 half4 __attribute__((ext_vector_type(4)));
typedef float    floatx4 __attribute__((ext_vector_type(4)));

#define MFMA(a, b, c) __builtin_amdgcn_mfma_f32_16x16x32_f16((a), (b), (c), 0, 0, 0)

__global__ __launch_bounds__(1024, 4) void gru_pipe(
    const float* __restrict__ enc,     // (B, 64)
    const float* __restrict__ emb_w,   // (64, 64)
    const float* __restrict__ emb_b,   // (64,)
    const float* __restrict__ w_ih,    // (3, 192, 64)
    const float* __restrict__ w_hh,    // (3, 192, 64)
    const float* __restrict__ b_ih,    // (3, 192)
    const float* __restrict__ b_hh,    // (3, 192)
    const float* __restrict__ out_w,   // (2, 64)
    const float* __restrict__ out_b,   // (2,)
    float* __restrict__ out)           // (B, 128, 2)
{
    __shared__ _Float16 s_emb[2 * TB];                   // emb out, parity = slot&1
    __shared__ _Float16 s_hl[NLAY * TILES * 2 * TB];     // h_l fp16, parity = t&1
    __shared__ float    s_hc[NLAY * TILES * 64 * TILE];  // fp32 carry, col-major

    const int tid   = threadIdx.x;
    const int wave  = tid >> 6, lane = tid & 63;
    const int stage = wave >> 2, g = wave & 3;           // stage 0..3, colgroup 0..3
    const int q = lane >> 4, c = lane & 15;
    const int u = (g << 4) | c;                          // owned hidden column
    const long wgbase = (long)blockIdx.x * (TILES * TILE);

    // ---- stage enc (= x(0) = h(-1)) into s_hl[l][j][parity=1] for all l,j ----
    {
        const int row = tid >> 4;            // 0..63 (tile j = row>>4, r = row&15)
        const int k0  = (tid & 15) << 2;     // 4 floats per thread
        const int j = row >> 4, rr = row & 15;
        floatx4 v = *(const floatx4*)(enc + (wgbase + row) * ESZ + k0);
        half4 h;
        #pragma unroll
        for (int x = 0; x < 4; ++x) h[x] = (_Float16)v[x];
        #pragma unroll
        for (int l = 0; l < NLAY; ++l)
            *(half4*)&s_hl[((l * TILES + j) * 2 + 1) * TB + rr * LDW + k0] = h;
    }

    // ---- per-stage weight fragments (union: stage0 uses [0..3], L uses [0..11]) ----
    auto ldw8s = [&](const float* p, float sc) {
        floatx4 a = *(const floatx4*)p, b = *(const floatx4*)(p + 4);
        half8 v;
        #pragma unroll
        for (int x = 0; x < 4; ++x) { v[x] = (_Float16)(a[x] * sc); v[4 + x] = (_Float16)(b[x] * sc); }
        return v;
    };
    half8 frag[12];
    float bias0 = 0.f, bias1 = 0.f, bias2 = 0.f, bias3 = 0.f;
    if (stage == 0) {
        frag[0] = ldw8s(emb_w + u * ESZ + q * 8, 1.f);
        frag[1] = ldw8s(emb_w + u * ESZ + 32 + q * 8, 1.f);
        const int oc = (c < NOUTC) ? c : 0;              // lanes c>=2 compute garbage, never stored
        frag[2] = ldw8s(out_w + oc * HSZ + q * 8, 1.f);
        frag[3] = ldw8s(out_w + oc * HSZ + 32 + q * 8, 1.f);
        bias0 = emb_b[u];
        bias1 = (c < NOUTC) ? out_b[c] : 0.f;
    } else {
        const int l = stage - 1;
        const float* wi = w_ih + l * 3 * HSZ * ESZ;
        const float* wh = w_hh + l * 3 * HSZ * ESZ;
        // r,z scaled by -log2e (sigmoid = rcp(1+exp2(acc))); n scaled by 2*log2e
        // (tanh = 1 - 2*rcp(1+exp2(acc))).
        frag[0]  = ldw8s(wi + (u) * ESZ + q * 8, -L2E);       frag[1]  = ldw8s(wi + (u) * ESZ + 32 + q * 8, -L2E);
        frag[2]  = ldw8s(wh + (u) * ESZ + q * 8, -L2E);       frag[3]  = ldw8s(wh + (u) * ESZ + 32 + q * 8, -L2E);
        frag[4]  = ldw8s(wi + (64 + u) * ESZ + q * 8, -L2E);  frag[5]  = ldw8s(wi + (64 + u) * ESZ + 32 + q * 8, -L2E);
        frag[6]  = ldw8s(wh + (64 + u) * ESZ + q * 8, -L2E);  frag[7]  = ldw8s(wh + (64 + u) * ESZ + 32 + q * 8, -L2E);
        frag[8]  = ldw8s(wi + (128 + u) * ESZ + q * 8, 2*L2E); frag[9]  = ldw8s(wi + (128 + u) * ESZ + 32 + q * 8, 2*L2E);
        frag[10] = ldw8s(wh + (128 + u) * ESZ + q * 8, 2*L2E); frag[11] = ldw8s(wh + (128 + u) * ESZ + 32 + q * 8, 2*L2E);
        const int b0 = l * 3 * HSZ;
        bias0 = -L2E * (b_ih[b0 + u] + b_hh[b0 + u]);
        bias1 = -L2E * (b_ih[b0 + 64 + u] + b_hh[b0 + 64 + u]);
        bias2 = 2.f * L2E * b_ih[b0 + 128 + u];
        bias3 = 2.f * L2E * b_hh[b0 + 128 + u];
        // fp32 carry init: lane owns col u, rows 4q..4q+3, all 4 tiles
        #pragma unroll
        for (int jt = 0; jt < TILES; ++jt) {
            floatx4 hv;
            #pragma unroll
            for (int i = 0; i < 4; ++i)
                hv[i] = enc[(wgbase + jt * TILE + q * 4 + i) * ESZ + u];
            *(floatx4*)&s_hc[((l * TILES + jt) * 64 + u) * TILE + q * 4] = hv;
        }
    }
    __syncthreads();

    // ---- skewed slot loop: tile j, time t at slot s = j + 4t + stage ----
    for (int s = 0; s < 4 * TLEN + TILES; ++s) {         // 516 slots
        const int j = (s - stage) & 3;
        const int t = (s - stage) >> 2;                  // negative -> inactive
        if (stage == 0) {
            if (t >= 0) {                                // t <= 128 by loop bound
                // x = h2(t-1)  (t=0: preinit enc at parity 1)
                const _Float16* xb = &s_hl[((2 * TILES + j) * 2 + ((t + 1) & 1)) * TB];
                const int ar = c * LDW + q * 8;
                half8 a0 = *(const half8*)&xb[ar];
                half8 a1 = *(const half8*)&xb[ar + 32];
                if (t >= 1 && g == 0) {                  // out(t-1) = h2(t-1) @ out_w.T + out_b
                    floatx4 acc = {bias1, bias1, bias1, bias1};
                    acc = MFMA(a0, frag[2], acc);
                    acc = MFMA(a1, frag[3], acc);
                    if (c < NOUTC) {
                        #pragma unroll
                        for (int i = 0; i < 4; ++i)
                            out[((wgbase + j * TILE + q * 4 + i) * TLEN + (t - 1)) * NOUTC + c] = acc[i];
                    }
                }
                if (t < TLEN) {                          // inp(t) = x @ emb_w.T + emb_b
                    floatx4 acc = {bias0, bias0, bias0, bias0};
                    acc = MFMA(a0, frag[0], acc);
                    acc = MFMA(a1, frag[1], acc);
                    _Float16* eb = &s_emb[(s & 1) * TB];
                    #pragma unroll
                    for (int i = 0; i < 4; ++i)
                        eb[(q * 4 + i) * LDW + u] = (_Float16)acc[i];
                }
            }
        } else {
            if (t >= 0 && t < TLEN) {
                const int l = stage - 1;
                const _Float16* xb = (stage == 1)
                    ? &s_emb[((s - 1) & 1) * TB]
                    : &s_hl[(((l - 1) * TILES + j) * 2 + (t & 1)) * TB];
                const _Float16* hb = &s_hl[((l * TILES + j) * 2 + ((t + 1) & 1)) * TB];
                const int ar = c * LDW + q * 8;
                half8 ax0 = *(const half8*)&xb[ar];
                half8 ax1 = *(const half8*)&xb[ar + 32];
                half8 ah0 = *(const half8*)&hb[ar];
                half8 ah1 = *(const half8*)&hb[ar + 32];
                float* hc = &s_hc[((l * TILES + j) * 64 + u) * TILE + q * 4];
                floatx4 hold = *(const floatx4*)hc;
                floatx4 accr  = {bias0, bias0, bias0, bias0};
                floatx4 accz  = {bias1, bias1, bias1, bias1};
                floatx4 accni = {bias2, bias2, bias2, bias2};
                floatx4 accnh = {bias3, bias3, bias3, bias3};
                accr  = MFMA(ax0, frag[0], accr);  accr  = MFMA(ax1, frag[1], accr);
                accr  = MFMA(ah0, frag[2], accr);  accr  = MFMA(ah1, frag[3], accr);
                accz  = MFMA(ax0, frag[4], accz);  accz  = MFMA(ax1, frag[5], accz);
                accz  = MFMA(ah0, frag[6], accz);  accz  = MFMA(ah1, frag[7], accz);
                accni = MFMA(ax0, frag[8], accni); accni = MFMA(ax1, frag[9], accni);
                accnh = MFMA(ah0, frag[10], accnh); accnh = MFMA(ah1, frag[11], accnh);
                _Float16* hw = &s_hl[((l * TILES + j) * 2 + (t & 1)) * TB];
                floatx4 hnew;
                #pragma unroll
                for (int i = 0; i < 4; ++i) {
                    const float r  = __builtin_amdgcn_rcpf(1.f + __builtin_amdgcn_exp2f(accr[i]));
                    const float z  = __builtin_amdgcn_rcpf(1.f + __builtin_amdgcn_exp2f(accz[i]));
                    const float a  = accni[i] + r * accnh[i];
                    const float n  = 1.f - 2.f * __builtin_amdgcn_rcpf(1.f + __builtin_amdgcn_exp2f(a));
                    const float hv = n + z * (hold[i] - n);
                    hnew[i] = hv;
                    hw[(q * 4 + i) * LDW + u] = (_Float16)hv;
                }
                *(floatx4*)hc = hnew;
            }
        }
        __syncthreads();
    }
}

extern "C" void kernel_launch(void* const* d_in, const int* in_sizes, int n_in,
                              void* d_out, int out_size, void* d_ws, size_t ws_size,
                              hipStream_t stream) {
    (void)in_sizes; (void)n_in; (void)d_ws; (void)ws_size; (void)out_size;
    const int grid = 16384 / (TILES * TILE);   // 256 workgroups, 1 per CU
    gru_pipe<<<grid, 1024, 0, stream>>>(
        (const float*)d_in[0],  // agentFutureTrajEnc
        (const float*)d_in[1],  // emb_w
        (const float*)d_in[2],  // emb_b
        (const float*)d_in[3],  // w_ih
        (const float*)d_in[4],  // w_hh
        (const float*)d_in[5],  // b_ih
        (const float*)d_in[6],  // b_hh
        (const float*)d_in[7],  // out_w
        (const float*)d_in[8],  // out_b
        (float*)d_out);
}

// Round 6
// 490.337 us; speedup vs baseline: 1.2283x; 1.0563x over previous
//
#include <hip/hip_runtime.h>

// FutureTrajDecoder: 3-layer GRU rollout, B=16384, ES=HS=64, T=128, NOUT=2.
// Stage-pipelined persistent kernel: 256 WGs x 1024 threads (16 waves).
// stage = wave>>2 in {0: emb+out-proj, 1: L0, 2: L1, 3: L2}; g = wave&3 owns
// 16 hidden cols. WG owns 4 batch tiles of 16 rows, skewed one barrier-slot
// apart. fp32 h-carry in VGPRs indexed by slot PHASE (s&3), static under a
// 4x unroll of the slot loop (phase p serves tile (p-stage)&3 for a wave).
// R6 fix vs R5: stage-1 emb-read parity was `js ^ 1` (=2,3 for js=2,3 — OOB
// into s_hl, corrupting x for two of four L0 tiles); correct parity is
// (js&1)^1, the literal translation of (s-1)&1 under s=4*s4+js.
// Gate scales folded into weights; biases in MFMA C-init. Activations fp16
// in LDS; MFMA 16x16x32 f16, fp32 accum.

#define ESZ   64
#define HSZ   64
#define NLAY  3
#define TLEN  128
#define NOUTC 2
#define TILE  16
#define TILES 4
#define LDW   72              // fp16 row stride (144 B): A-frag reads conflict-free
#define TB    (TILE*LDW)
#define L2E   1.44269504f

typedef _Float16 half8 __attribute__((ext_vector_type(8)));
typedef _Float16 half4 __attribute__((ext_vector_type(4)));
typedef float    floatx4 __attribute__((ext_vector_type(4)));

#define MFMA(a, b, c) __builtin_amdgcn_mfma_f32_16x16x32_f16((a), (b), (c), 0, 0, 0)

__global__ __launch_bounds__(1024, 4) void gru_pipe(
    const float* __restrict__ enc,     // (B, 64)
    const float* __restrict__ emb_w,   // (64, 64)
    const float* __restrict__ emb_b,   // (64,)
    const float* __restrict__ w_ih,    // (3, 192, 64)
    const float* __restrict__ w_hh,    // (3, 192, 64)
    const float* __restrict__ b_ih,    // (3, 192)
    const float* __restrict__ b_hh,    // (3, 192)
    const float* __restrict__ out_w,   // (2, 64)
    const float* __restrict__ out_b,   // (2,)
    float* __restrict__ out)           // (B, 128, 2)
{
    __shared__ _Float16 s_emb[2 * TB];                   // emb out, parity = slot&1
    __shared__ _Float16 s_hl[NLAY * TILES * 2 * TB];     // h_l fp16, parity = t&1

    const int tid   = threadIdx.x;
    const int wave  = tid >> 6, lane = tid & 63;
    const int stage = wave >> 2, g = wave & 3;           // stage 0..3, colgroup 0..3
    const int q = lane >> 4, c = lane & 15;
    const int u = (g << 4) | c;                          // owned hidden column
    const long wgbase = (long)blockIdx.x * (TILES * TILE);

    // ---- stage enc (= x(0) = h(-1)) into s_hl[l][j][parity=1] for all l,j ----
    {
        const int row = tid >> 4;            // 0..63
        const int k0  = (tid & 15) << 2;     // 4 floats per thread
        const int j = row >> 4, rr = row & 15;
        floatx4 v = *(const floatx4*)(enc + (wgbase + row) * ESZ + k0);
        half4 h;
        #pragma unroll
        for (int x = 0; x < 4; ++x) h[x] = (_Float16)v[x];
        #pragma unroll
        for (int l = 0; l < NLAY; ++l)
            *(half4*)&s_hl[((l * TILES + j) * 2 + 1) * TB + rr * LDW + k0] = h;
    }

    // ---- per-stage weight fragments ----
    auto ldw8s = [&](const float* p, float sc) {
        floatx4 a = *(const floatx4*)p, b = *(const floatx4*)(p + 4);
        half8 v;
        #pragma unroll
        for (int x = 0; x < 4; ++x) { v[x] = (_Float16)(a[x] * sc); v[4 + x] = (_Float16)(b[x] * sc); }
        return v;
    };
    half8 frag[12];
    float bias0 = 0.f, bias1 = 0.f, bias2 = 0.f, bias3 = 0.f;
    if (stage == 0) {
        frag[0] = ldw8s(emb_w + u * ESZ + q * 8, 1.f);
        frag[1] = ldw8s(emb_w + u * ESZ + 32 + q * 8, 1.f);
        const int oc = (c < NOUTC) ? c : 0;              // lanes c>=2 compute garbage, never stored
        frag[2] = ldw8s(out_w + oc * HSZ + q * 8, 1.f);
        frag[3] = ldw8s(out_w + oc * HSZ + 32 + q * 8, 1.f);
        bias0 = emb_b[u];
        bias1 = (c < NOUTC) ? out_b[c] : 0.f;
    } else {
        const int l = stage - 1;
        const float* wi = w_ih + l * 3 * HSZ * ESZ;
        const float* wh = w_hh + l * 3 * HSZ * ESZ;
        // r,z scaled by -log2e (sigmoid = rcp(1+exp2(acc))); n by 2*log2e
        // (tanh = 1 - 2*rcp(1+exp2(acc))).
        frag[0]  = ldw8s(wi + (u) * ESZ + q * 8, -L2E);       frag[1]  = ldw8s(wi + (u) * ESZ + 32 + q * 8, -L2E);
        frag[2]  = ldw8s(wh + (u) * ESZ + q * 8, -L2E);       frag[3]  = ldw8s(wh + (u) * ESZ + 32 + q * 8, -L2E);
        frag[4]  = ldw8s(wi + (64 + u) * ESZ + q * 8, -L2E);  frag[5]  = ldw8s(wi + (64 + u) * ESZ + 32 + q * 8, -L2E);
        frag[6]  = ldw8s(wh + (64 + u) * ESZ + q * 8, -L2E);  frag[7]  = ldw8s(wh + (64 + u) * ESZ + 32 + q * 8, -L2E);
        frag[8]  = ldw8s(wi + (128 + u) * ESZ + q * 8, 2*L2E); frag[9]  = ldw8s(wi + (128 + u) * ESZ + 32 + q * 8, 2*L2E);
        frag[10] = ldw8s(wh + (128 + u) * ESZ + q * 8, 2*L2E); frag[11] = ldw8s(wh + (128 + u) * ESZ + 32 + q * 8, 2*L2E);
        const int b0 = l * 3 * HSZ;
        bias0 = -L2E * (b_ih[b0 + u] + b_hh[b0 + u]);
        bias1 = -L2E * (b_ih[b0 + 64 + u] + b_hh[b0 + 64 + u]);
        bias2 = 2.f * L2E * b_ih[b0 + 128 + u];
        bias3 = 2.f * L2E * b_hh[b0 + 128 + u];
    }

    // ---- fp32 h-carry in VGPRs, indexed by slot phase p (static):
    //      phase p serves tile (p - stage) & 3 for this wave ----
    floatx4 carr0 = {0,0,0,0}, carr1 = {0,0,0,0}, carr2 = {0,0,0,0}, carr3 = {0,0,0,0};
    if (stage >= 1) {
        floatx4 tmp[4];
        #pragma unroll
        for (int p = 0; p < 4; ++p) {
            const int jp = (p - stage) & 3;
            floatx4 hv;
            #pragma unroll
            for (int i = 0; i < 4; ++i)
                hv[i] = enc[(wgbase + jp * TILE + q * 4 + i) * ESZ + u];
            tmp[p] = hv;
        }
        carr0 = tmp[0]; carr1 = tmp[1]; carr2 = tmp[2]; carr3 = tmp[3];
    }
    const int ar = c * LDW + q * 8;                      // A-frag elem offset (hoisted)
    __syncthreads();

    // ---- slot loop, 4x unrolled by phase js = s&3 ----
    auto phase = [&](const int js, floatx4& carr, const int s4) {
        if (stage == 0) {
            const int j = js;                            // sigma = 0
            const int t = s4;
            // x = h2(t-1)  (t=0: preinit enc at parity 1)
            const _Float16* xb = &s_hl[((2 * TILES + j) * 2 + ((t + 1) & 1)) * TB];
            half8 a0 = *(const half8*)&xb[ar];
            half8 a1 = *(const half8*)&xb[ar + 32];
            if (t >= 1 && g == 0) {                      // out(t-1) = h2(t-1) @ out_w.T + out_b
                floatx4 acc = {bias1, bias1, bias1, bias1};
                acc = MFMA(a0, frag[2], acc);
                acc = MFMA(a1, frag[3], acc);
                if (c < NOUTC) {
                    #pragma unroll
                    for (int i = 0; i < 4; ++i)
                        out[((wgbase + j * TILE + q * 4 + i) * TLEN + (t - 1)) * NOUTC + c] = acc[i];
                }
            }
            if (t < TLEN) {                              // inp(t) = x @ emb_w.T + emb_b
                floatx4 acc = {bias0, bias0, bias0, bias0};
                acc = MFMA(a0, frag[0], acc);
                acc = MFMA(a1, frag[1], acc);
                _Float16* eb = &s_emb[(js & 1) * TB];    // compile-time parity (s&1 = js&1)
                #pragma unroll
                for (int i = 0; i < 4; ++i)
                    eb[(q * 4 + i) * LDW + u] = (_Float16)acc[i];
            }
        } else {
            const int l = stage - 1;
            const int j = (js - stage) & 3;
            const int t = s4 - ((js < stage) ? 1 : 0);
            if (t >= 0 && t < TLEN) {
                const _Float16* xb = (stage == 1)
                    ? &s_emb[(((js & 1) ^ 1)) * TB]      // parity (s-1)&1 under s=4*s4+js
                    : &s_hl[(((l - 1) * TILES + j) * 2 + (t & 1)) * TB];
                const _Float16* hb = &s_hl[((l * TILES + j) * 2 + ((t + 1) & 1)) * TB];
                half8 ax0 = *(const half8*)&xb[ar];
                half8 ax1 = *(const half8*)&xb[ar + 32];
                half8 ah0 = *(const half8*)&hb[ar];
                half8 ah1 = *(const half8*)&hb[ar + 32];
                floatx4 hold = carr;
                floatx4 accr  = {bias0, bias0, bias0, bias0};
                floatx4 accz  = {bias1, bias1, bias1, bias1};
                floatx4 accni = {bias2, bias2, bias2, bias2};
                floatx4 accnh = {bias3, bias3, bias3, bias3};
                accr  = MFMA(ax0, frag[0], accr);  accr  = MFMA(ax1, frag[1], accr);
                accr  = MFMA(ah0, frag[2], accr);  accr  = MFMA(ah1, frag[3], accr);
                accz  = MFMA(ax0, frag[4], accz);  accz  = MFMA(ax1, frag[5], accz);
                accz  = MFMA(ah0, frag[6], accz);  accz  = MFMA(ah1, frag[7], accz);
                accni = MFMA(ax0, frag[8], accni); accni = MFMA(ax1, frag[9], accni);
                accnh = MFMA(ah0, frag[10], accnh); accnh = MFMA(ah1, frag[11], accnh);
                _Float16* hw = &s_hl[((l * TILES + j) * 2 + (t & 1)) * TB];
                floatx4 hnew;
                #pragma unroll
                for (int i = 0; i < 4; ++i) {
                    const float r  = __builtin_amdgcn_rcpf(1.f + __builtin_amdgcn_exp2f(accr[i]));
                    const float z  = __builtin_amdgcn_rcpf(1.f + __builtin_amdgcn_exp2f(accz[i]));
                    const float a  = accni[i] + r * accnh[i];
                    const float n  = 1.f - 2.f * __builtin_amdgcn_rcpf(1.f + __builtin_amdgcn_exp2f(a));
                    const float hv = n + z * (hold[i] - n);
                    hnew[i] = hv;
                    hw[(q * 4 + i) * LDW + u] = (_Float16)hv;
                }
                carr = hnew;
            }
        }
        __syncthreads();
    };

    for (int s4 = 0; s4 <= TLEN; ++s4) {                 // 129 iters x 4 phases = 516 slots
        phase(0, carr0, s4);
        phase(1, carr1, s4);
        phase(2, carr2, s4);
        phase(3, carr3, s4);
    }
}

extern "C" void kernel_launch(void* const* d_in, const int* in_sizes, int n_in,
                              void* d_out, int out_size, void* d_ws, size_t ws_size,
                              hipStream_t stream) {
    (void)in_sizes; (void)n_in; (void)d_ws; (void)ws_size; (void)out_size;
    const int grid = 16384 / (TILES * TILE);   // 256 workgroups, 1 per CU
    gru_pipe<<<grid, 1024, 0, stream>>>(
        (const float*)d_in[0],  // agentFutureTrajEnc
        (const float*)d_in[1],  // emb_w
        (const float*)d_in[2],  // emb_b
        (const float*)d_in[3],  // w_ih
        (const float*)d_in[4],  // w_hh
        (const float*)d_in[5],  // b_ih
        (const float*)d_in[6],  // b_hh
        (const float*)d_in[7],  // out_w
        (const float*)d_in[8],  // out_b
        (float*)d_out);
}

// Round 7
// 490.226 us; speedup vs baseline: 1.2286x; 1.0002x over previous
//
#include <hip/hip_runtime.h>

// FutureTrajDecoder: 3-layer GRU rollout, B=16384, ES=HS=64, T=128, NOUT=2.
// R7: 3-stage pipeline (emb folded into L0), 256 WGs x 768 threads (12 waves).
// stage l = wave>>2 = GRU layer; g = wave&3 owns 16 hidden cols. WG owns 4
// batch tiles of 16 rows, skewed one barrier-slot apart (slot s: stage l
// does tile j, time t with 4t+j+l = s).
//  - Emb fold: W' = W_ih0 @ W_e, b' = W_ih0 @ b_e + b_ih0 computed in-kernel
//    (one-time fp32 fold, ~3us); L0's x-input is then h2(t-1) directly, so
//    the emb stage and its LDS traffic vanish. Out-proj rides on L0's g0
//    wave reusing the same h2(t-1) A-fragments (2 extra MFMAs, 0 extra LDS).
//  - h-operand prefetch: h_l(t-1) for slot s+1 was written at s-3 (L0's x at
//    s-1) -> ds_reads issued one slot early; post-barrier path loses ~120cyc.
//  - lgkm-only barrier (asm s_waitcnt lgkmcnt(0) + s_barrier): out-stores
//    never force a vmcnt(0) drain (nobody reads `out` in-kernel).
// fp32 h-carry in VGPRs (phase-indexed, static under 4x phase unroll);
// gate scales folded into weights; biases in MFMA C-init; activations fp16
// in LDS; MFMA 16x16x32 f16, fp32 accumulate.

#define ESZ   64
#define HSZ   64
#define NLAY  3
#define TLEN  128
#define NOUTC 2
#define TILE  16
#define TILES 4
#define LDW   72              // fp16 row stride (144 B): A-frag b128 reads conflict-free
#define TB    (TILE*LDW)
#define L2E   1.44269504f

typedef _Float16 half8 __attribute__((ext_vector_type(8)));
typedef float    floatx4 __attribute__((ext_vector_type(4)));

#define MFMA(a, b, c) __builtin_amdgcn_mfma_f32_16x16x32_f16((a), (b), (c), 0, 0, 0)

__device__ __forceinline__ void wg_barrier() {
    asm volatile("s_waitcnt lgkmcnt(0)" ::: "memory");
    __builtin_amdgcn_s_barrier();
    asm volatile("" ::: "memory");
}

__global__ __launch_bounds__(768, 3) void gru_pipe(
    const float* __restrict__ enc,     // (B, 64)
    const float* __restrict__ emb_w,   // (64, 64)
    const float* __restrict__ emb_b,   // (64,)
    const float* __restrict__ w_ih,    // (3, 192, 64)
    const float* __restrict__ w_hh,    // (3, 192, 64)
    const float* __restrict__ b_ih,    // (3, 192)
    const float* __restrict__ b_hh,    // (3, 192)
    const float* __restrict__ out_w,   // (2, 64)
    const float* __restrict__ out_b,   // (2,)
    float* __restrict__ out)           // (B, 128, 2)
{
    __shared__ _Float16 s_hl[NLAY * TILES * 2 * TB];     // h_l fp16, parity = t&1

    const int tid  = threadIdx.x;
    const int wave = tid >> 6, lane = tid & 63;
    const int l = wave >> 2, g = wave & 3;               // layer-stage 0..2, colgroup 0..3
    const int q = lane >> 4, c = lane & 15;
    const int u = (g << 4) | c;                          // owned hidden column
    const long wgbase = (long)blockIdx.x * (TILES * TILE);

    // ---- stage enc (= x(0) = h(-1)) into all layer buffers, parity 1 ----
    if (tid < 512) {
        const int row = tid >> 3, k0 = (tid & 7) << 3;   // 8 floats per thread
        const int j = row >> 4, rr = row & 15;
        const float* p = enc + (wgbase + row) * ESZ + k0;
        floatx4 s0 = *(const floatx4*)p;
        floatx4 s1 = *(const floatx4*)(p + 4);
        half8 v;
        #pragma unroll
        for (int x = 0; x < 4; ++x) { v[x] = (_Float16)s0[x]; v[4 + x] = (_Float16)s1[x]; }
        #pragma unroll
        for (int ly = 0; ly < NLAY; ++ly)
            *(half8*)&s_hl[((ly * TILES + j) * 2 + 1) * TB + rr * LDW + k0] = v;
    }

    // ---- weights: frags [x-half0, x-half1, h-half0, h-half1] per gate ----
    auto ldw8s = [&](const float* p, float sc) {
        floatx4 a = *(const floatx4*)p, b = *(const floatx4*)(p + 4);
        half8 v;
        #pragma unroll
        for (int x = 0; x < 4; ++x) { v[x] = (_Float16)(a[x] * sc); v[4 + x] = (_Float16)(b[x] * sc); }
        return v;
    };
    half8 fR[4], fZ[4], fNi[2], fNh[2], fO[2];
    float bias0, bias1, bias2, bias3, outb = 0.f;
    if (l == 0) {
        // ---- fold W' = W_ih0 @ W_e (fp32), b' = W_ih0 @ b_e + b_ih0 ----
        const float* wi = w_ih;            // layer 0
        const float* wh = w_hh;
        floatx4 aR[4], aZ[4], aN[4];
        #pragma unroll
        for (int x = 0; x < 4; ++x) { aR[x] = {0,0,0,0}; aZ[x] = {0,0,0,0}; aN[x] = {0,0,0,0}; }
        float bR = 0.f, bZ = 0.f, bN = 0.f;
        for (int k4 = 0; k4 < 64; k4 += 4) {
            floatx4 wr4 = *(const floatx4*)(wi + (u) * 64 + k4);
            floatx4 wz4 = *(const floatx4*)(wi + (64 + u) * 64 + k4);
            floatx4 wn4 = *(const floatx4*)(wi + (128 + u) * 64 + k4);
            floatx4 be4 = *(const floatx4*)(emb_b + k4);
            #pragma unroll
            for (int kk = 0; kk < 4; ++kk) {
                const float* er = emb_w + (k4 + kk) * 64;
                floatx4 e0 = *(const floatx4*)(er + q * 8);
                floatx4 e1 = *(const floatx4*)(er + q * 8 + 4);
                floatx4 e2 = *(const floatx4*)(er + 32 + q * 8);
                floatx4 e3 = *(const floatx4*)(er + 32 + q * 8 + 4);
                const float wr = wr4[kk], wz = wz4[kk], wn = wn4[kk];
                aR[0] += wr * e0; aR[1] += wr * e1; aR[2] += wr * e2; aR[3] += wr * e3;
                aZ[0] += wz * e0; aZ[1] += wz * e1; aZ[2] += wz * e2; aZ[3] += wz * e3;
                aN[0] += wn * e0; aN[1] += wn * e1; aN[2] += wn * e2; aN[3] += wn * e3;
                bR += wr * be4[kk]; bZ += wz * be4[kk]; bN += wn * be4[kk];
            }
        }
        #pragma unroll
        for (int x = 0; x < 4; ++x) {
            fR[0][x] = (_Float16)(-L2E * aR[0][x]);   fR[0][4 + x] = (_Float16)(-L2E * aR[1][x]);
            fR[1][x] = (_Float16)(-L2E * aR[2][x]);   fR[1][4 + x] = (_Float16)(-L2E * aR[3][x]);
            fZ[0][x] = (_Float16)(-L2E * aZ[0][x]);   fZ[0][4 + x] = (_Float16)(-L2E * aZ[1][x]);
            fZ[1][x] = (_Float16)(-L2E * aZ[2][x]);   fZ[1][4 + x] = (_Float16)(-L2E * aZ[3][x]);
            fNi[0][x] = (_Float16)(2*L2E * aN[0][x]); fNi[0][4 + x] = (_Float16)(2*L2E * aN[1][x]);
            fNi[1][x] = (_Float16)(2*L2E * aN[2][x]); fNi[1][4 + x] = (_Float16)(2*L2E * aN[3][x]);
        }
        fR[2]  = ldw8s(wh + (u) * 64 + q * 8, -L2E);        fR[3]  = ldw8s(wh + (u) * 64 + 32 + q * 8, -L2E);
        fZ[2]  = ldw8s(wh + (64 + u) * 64 + q * 8, -L2E);   fZ[3]  = ldw8s(wh + (64 + u) * 64 + 32 + q * 8, -L2E);
        fNh[0] = ldw8s(wh + (128 + u) * 64 + q * 8, 2*L2E); fNh[1] = ldw8s(wh + (128 + u) * 64 + 32 + q * 8, 2*L2E);
        bias0 = -L2E * (bR + b_ih[u] + b_hh[u]);
        bias1 = -L2E * (bZ + b_ih[64 + u] + b_hh[64 + u]);
        bias2 = 2.f * L2E * (bN + b_ih[128 + u]);
        bias3 = 2.f * L2E * b_hh[128 + u];
        const int oc = (c < NOUTC) ? c : 0;
        fO[0] = ldw8s(out_w + oc * 64 + q * 8, 1.f);
        fO[1] = ldw8s(out_w + oc * 64 + 32 + q * 8, 1.f);
        outb = (c < NOUTC) ? out_b[c] : 0.f;
    } else {
        const float* wi = w_ih + l * 3 * HSZ * ESZ;
        const float* wh = w_hh + l * 3 * HSZ * ESZ;
        fR[0]  = ldw8s(wi + (u) * 64 + q * 8, -L2E);        fR[1]  = ldw8s(wi + (u) * 64 + 32 + q * 8, -L2E);
        fR[2]  = ldw8s(wh + (u) * 64 + q * 8, -L2E);        fR[3]  = ldw8s(wh + (u) * 64 + 32 + q * 8, -L2E);
        fZ[0]  = ldw8s(wi + (64 + u) * 64 + q * 8, -L2E);   fZ[1]  = ldw8s(wi + (64 + u) * 64 + 32 + q * 8, -L2E);
        fZ[2]  = ldw8s(wh + (64 + u) * 64 + q * 8, -L2E);   fZ[3]  = ldw8s(wh + (64 + u) * 64 + 32 + q * 8, -L2E);
        fNi[0] = ldw8s(wi + (128 + u) * 64 + q * 8, 2*L2E); fNi[1] = ldw8s(wi + (128 + u) * 64 + 32 + q * 8, 2*L2E);
        fNh[0] = ldw8s(wh + (128 + u) * 64 + q * 8, 2*L2E); fNh[1] = ldw8s(wh + (128 + u) * 64 + 32 + q * 8, 2*L2E);
        const int b0 = l * 3 * HSZ;
        bias0 = -L2E * (b_ih[b0 + u] + b_hh[b0 + u]);
        bias1 = -L2E * (b_ih[b0 + 64 + u] + b_hh[b0 + 64 + u]);
        bias2 = 2.f * L2E * b_ih[b0 + 128 + u];
        bias3 = 2.f * L2E * b_hh[b0 + 128 + u];
        fO[0] = fO[1] = half8{};
    }

    // ---- fp32 h-carry in VGPRs: phase p serves tile (p - l) & 3 ----
    floatx4 carr0, carr1, carr2, carr3;
    {
        floatx4 tmp[4];
        #pragma unroll
        for (int p = 0; p < 4; ++p) {
            const int jp = (p - l) & 3;
            floatx4 hv;
            #pragma unroll
            for (int i = 0; i < 4; ++i)
                hv[i] = enc[(wgbase + jp * TILE + q * 4 + i) * ESZ + u];
            tmp[p] = hv;
        }
        carr0 = tmp[0]; carr1 = tmp[1]; carr2 = tmp[2]; carr3 = tmp[3];
    }
    const int ar = c * LDW + q * 8;                      // A-frag elem offset
    __syncthreads();

    // ---- gate body (shared) ----
    auto gru = [&](half8 ax0, half8 ax1, half8 ah0, half8 ah1, floatx4& carr, _Float16* hw) {
        floatx4 accr  = {bias0, bias0, bias0, bias0};
        floatx4 accz  = {bias1, bias1, bias1, bias1};
        floatx4 accni = {bias2, bias2, bias2, bias2};
        floatx4 accnh = {bias3, bias3, bias3, bias3};
        accr  = MFMA(ah0, fR[2], accr);   accr  = MFMA(ah1, fR[3], accr);
        accz  = MFMA(ah0, fZ[2], accz);   accz  = MFMA(ah1, fZ[3], accz);
        accnh = MFMA(ah0, fNh[0], accnh); accnh = MFMA(ah1, fNh[1], accnh);
        accr  = MFMA(ax0, fR[0], accr);   accr  = MFMA(ax1, fR[1], accr);
        accz  = MFMA(ax0, fZ[0], accz);   accz  = MFMA(ax1, fZ[1], accz);
        accni = MFMA(ax0, fNi[0], accni); accni = MFMA(ax1, fNi[1], accni);
        const floatx4 hold = carr;
        floatx4 hnew;
        #pragma unroll
        for (int i = 0; i < 4; ++i) {
            const float r  = __builtin_amdgcn_rcpf(1.f + __builtin_amdgcn_exp2f(accr[i]));
            const float z  = __builtin_amdgcn_rcpf(1.f + __builtin_amdgcn_exp2f(accz[i]));
            const float a  = accni[i] + r * accnh[i];
            const float n  = 1.f - 2.f * __builtin_amdgcn_rcpf(1.f + __builtin_amdgcn_exp2f(a));
            const float hv = n + z * (hold[i] - n);
            hnew[i] = hv;
            hw[(q * 4 + i) * LDW + u] = (_Float16)hv;
        }
        carr = hnew;
    };

    // ---- prefetch registers (filled one slot ahead) ----
    half8 ah0p, ah1p, ax0p{}, ax1p{};
    {   // prologue: phase js=0, s4=0
        const int jn = (0 - l) & 3;
        const int tn = (l > 0) ? -1 : 0;
        const _Float16* hb = &s_hl[((l * TILES + jn) * 2 + ((tn + 1) & 1)) * TB];
        ah0p = *(const half8*)&hb[ar];
        ah1p = *(const half8*)&hb[ar + 32];
        if (l == 0) {
            const _Float16* xb = &s_hl[((2 * TILES + jn) * 2 + ((tn + 1) & 1)) * TB];
            ax0p = *(const half8*)&xb[ar];
            ax1p = *(const half8*)&xb[ar + 32];
        }
    }

    // ---- slot loop, 4x unrolled by phase js = s&3 ----
    auto phase = [&](const int js, floatx4& carr, const int s4) {
        const int j = (js - l) & 3;
        const int t = s4 - ((js < l) ? 1 : 0);
        // current operands from prefetch regs
        const half8 ah0 = ah0p, ah1 = ah1p, ax0 = ax0p, ax1 = ax1p;
        // issue prefetch for next phase (slot s+1); data written <= slot s-1
        {
            const int jsn = (js + 1) & 3;
            const int s4n = s4 + ((js == 3) ? 1 : 0);
            const int jn  = (jsn - l) & 3;
            const int tn  = s4n - ((jsn < l) ? 1 : 0);
            const int par = (tn + 1) & 1;
            const _Float16* hb = &s_hl[((l * TILES + jn) * 2 + par) * TB];
            ah0p = *(const half8*)&hb[ar];
            ah1p = *(const half8*)&hb[ar + 32];
            if (l == 0) {
                const _Float16* xb = &s_hl[((2 * TILES + jn) * 2 + par) * TB];
                ax0p = *(const half8*)&xb[ar];
                ax1p = *(const half8*)&xb[ar + 32];
            }
        }
        if (l == 0) {
            if (t >= 1 && g == 0) {                      // out(t-1) = h2(t-1) @ out_w.T + out_b
                floatx4 acc = {outb, outb, outb, outb};
                acc = MFMA(ax0, fO[0], acc);
                acc = MFMA(ax1, fO[1], acc);
                if (c < NOUTC) {
                    #pragma unroll
                    for (int i = 0; i < 4; ++i)
                        out[((wgbase + j * TILE + q * 4 + i) * TLEN + (t - 1)) * NOUTC + c] = acc[i];
                }
            }
            if (t < TLEN)                                // h0(t) from x = h2(t-1) via folded W'
                gru(ax0, ax1, ah0, ah1, carr, &s_hl[((0 * TILES + j) * 2 + (t & 1)) * TB]);
        } else {
            if (t >= 0 && t < TLEN) {
                const _Float16* xb = &s_hl[(((l - 1) * TILES + j) * 2 + (t & 1)) * TB];
                half8 bx0 = *(const half8*)&xb[ar];      // post-barrier read; latency
                half8 bx1 = *(const half8*)&xb[ar + 32]; // overlapped by h-MFMAs in gru
                gru(bx0, bx1, ah0, ah1, carr, &s_hl[((l * TILES + j) * 2 + (t & 1)) * TB]);
            }
        }
        wg_barrier();
    };

    for (int s4 = 0; s4 <= TLEN; ++s4) {                 // 129 x 4 phases = 516 slots
        phase(0, carr0, s4);
        phase(1, carr1, s4);
        phase(2, carr2, s4);
        phase(3, carr3, s4);
    }
}

extern "C" void kernel_launch(void* const* d_in, const int* in_sizes, int n_in,
                              void* d_out, int out_size, void* d_ws, size_t ws_size,
                              hipStream_t stream) {
    (void)in_sizes; (void)n_in; (void)d_ws; (void)ws_size; (void)out_size;
    const int grid = 16384 / (TILES * TILE);   // 256 workgroups, 1 per CU
    gru_pipe<<<grid, 768, 0, stream>>>(
        (const float*)d_in[0],  // agentFutureTrajEnc
        (const float*)d_in[1],  // emb_w
        (const float*)d_in[2],  // emb_b
        (const float*)d_in[3],  // w_ih
        (const float*)d_in[4],  // w_hh
        (const float*)d_in[5],  // b_ih
        (const float*)d_in[6],  // b_hh
        (const float*)d_in[7],  // out_w
        (const float*)d_in[8],  // out_b
        (float*)d_out);
}

// Round 8
// 448.343 us; speedup vs baseline: 1.3433x; 1.0934x over previous
//
#include <hip/hip_runtime.h>

// FutureTrajDecoder: 3-layer GRU rollout, B=16384, ES=HS=64, T=128, NOUT=2.
// R8: barrier-free producer/consumer pipeline. 256 WGs x 768 thr (12 waves):
// wave>>2 = GRU layer stage (emb folded into L0; out-proj on L0/g0 wave),
// wave&3 = 16-col hidden group. WG owns 4 batch tiles x 16 rows.
// Sync: per-(layer,tile) generation counters in LDS. Producer: waitcnt
// lgkmcnt(0) then lane0 atomicAdd(+1) after writing its h-slice (counter
// hits 4(t+1) when all 4 col-groups done). Consumer: spin on one broadcast
// volatile ds_read until >= target. No s_barrier in the main loop -> no
// 12-wave convoy, no global drain; waves self-schedule down the ring
// L0->L1->L2->L0(t+1). Anti-deps (parity-buffer overwrite) are covered by
// the ring chain + per-wave program order (writer of h_l(t) transitively
// waits on every reader of h_l(t-2)).
// MFMA operand swap (weights=A, acts=B): C = [hidden=q*4+i][batch=c], so
// gate output is 4 contiguous f16 -> single ds_write_b64 (was 4x b16);
// biases become floatx4 C-inits. fp32 h-carry in VGPRs (per-tile, unrolled).
// Gate scales folded into weights. MFMA 16x16x32 f16, fp32 accumulate.

#define ESZ   64
#define HSZ   64
#define TLEN  128
#define NOUTC 2
#define LDW   72              // fp16 row stride (144 B)
#define TB    (16*LDW)
#define L2E   1.44269504f

typedef _Float16 half8 __attribute__((ext_vector_type(8)));
typedef _Float16 half4 __attribute__((ext_vector_type(4)));
typedef float    floatx4 __attribute__((ext_vector_type(4)));
typedef float    floatx2 __attribute__((ext_vector_type(2)));

#define MFMA(a, b, c) __builtin_amdgcn_mfma_f32_16x16x32_f16((a), (b), (c), 0, 0, 0)

__global__ __launch_bounds__(768, 3) void gru_pipe(
    const float* __restrict__ enc,     // (B, 64)
    const float* __restrict__ emb_w,   // (64, 64)
    const float* __restrict__ emb_b,   // (64,)
    const float* __restrict__ w_ih,    // (3, 192, 64)
    const float* __restrict__ w_hh,    // (3, 192, 64)
    const float* __restrict__ b_ih,    // (3, 192)
    const float* __restrict__ b_hh,    // (3, 192)
    const float* __restrict__ out_w,   // (2, 64)
    const float* __restrict__ out_b,   // (2,)
    float* __restrict__ out)           // (B, 128, 2)
{
    __shared__ _Float16 s_hl[3 * 4 * 2 * TB];   // h_l fp16 [layer][tile][parity=t&1]
    __shared__ float    s_btmp[3 * 64];         // folded emb bias (fp32)
    __shared__ int      s_flag[12];             // [layer][tile] generation counters

    const int tid  = threadIdx.x;
    const int wave = tid >> 6, lane = tid & 63;
    const int l = wave >> 2, g = wave & 3;      // layer-stage 0..2, colgroup 0..3
    const int q = lane >> 4, c = lane & 15;
    const int u  = (g << 4) | c;                // weight row this lane loads
    const int u4 = (g << 4) | (q << 2);         // first hidden unit this lane OWNS
    const long wgbase = (long)blockIdx.x * 64;

    // ---- stage enc (= x(0) = h(-1)) into all layer buffers, parity 1 ----
    if (tid < 512) {
        const int row = tid >> 3, k0 = (tid & 7) << 3;   // 8 floats per thread
        const int j = row >> 4, rr = row & 15;
        const float* p = enc + (wgbase + row) * ESZ + k0;
        floatx4 s0 = *(const floatx4*)p;
        floatx4 s1 = *(const floatx4*)(p + 4);
        half8 v;
        #pragma unroll
        for (int x = 0; x < 4; ++x) { v[x] = (_Float16)s0[x]; v[4 + x] = (_Float16)s1[x]; }
        #pragma unroll
        for (int ly = 0; ly < 3; ++ly)
            *(half8*)&s_hl[((ly * 4 + j) * 2 + 1) * TB + rr * LDW + k0] = v;
    }
    if (tid < 12) s_flag[tid] = 0;

    // ---- weight fragments (A-operand; identical byte layout to old B) ----
    auto ldw8s = [&](const float* p, float sc) {
        floatx4 a = *(const floatx4*)p, b = *(const floatx4*)(p + 4);
        half8 v;
        #pragma unroll
        for (int x = 0; x < 4; ++x) { v[x] = (_Float16)(a[x] * sc); v[4 + x] = (_Float16)(b[x] * sc); }
        return v;
    };
    half8 fR[4], fZ[4], fNi[2], fNh[2], fO[2];
    fO[0] = fO[1] = half8{};
    if (l == 0) {
        // ---- fold W' = W_ih0 @ W_e (fp32), b' = W_ih0 @ b_e ----
        const float* wi = w_ih;
        const float* wh = w_hh;
        floatx4 aR[4], aZ[4], aN[4];
        #pragma unroll
        for (int x = 0; x < 4; ++x) { aR[x] = {0,0,0,0}; aZ[x] = {0,0,0,0}; aN[x] = {0,0,0,0}; }
        float bR = 0.f, bZ = 0.f, bN = 0.f;
        for (int k4 = 0; k4 < 64; k4 += 4) {
            floatx4 wr4 = *(const floatx4*)(wi + (u) * 64 + k4);
            floatx4 wz4 = *(const floatx4*)(wi + (64 + u) * 64 + k4);
            floatx4 wn4 = *(const floatx4*)(wi + (128 + u) * 64 + k4);
            floatx4 be4 = *(const floatx4*)(emb_b + k4);
            #pragma unroll
            for (int kk = 0; kk < 4; ++kk) {
                const float* er = emb_w + (k4 + kk) * 64;
                floatx4 e0 = *(const floatx4*)(er + q * 8);
                floatx4 e1 = *(const floatx4*)(er + q * 8 + 4);
                floatx4 e2 = *(const floatx4*)(er + 32 + q * 8);
                floatx4 e3 = *(const floatx4*)(er + 32 + q * 8 + 4);
                const float wr = wr4[kk], wz = wz4[kk], wn = wn4[kk];
                aR[0] += wr * e0; aR[1] += wr * e1; aR[2] += wr * e2; aR[3] += wr * e3;
                aZ[0] += wz * e0; aZ[1] += wz * e1; aZ[2] += wz * e2; aZ[3] += wz * e3;
                aN[0] += wn * e0; aN[1] += wn * e1; aN[2] += wn * e2; aN[3] += wn * e3;
                bR += wr * be4[kk]; bZ += wz * be4[kk]; bN += wn * be4[kk];
            }
        }
        #pragma unroll
        for (int x = 0; x < 4; ++x) {
            fR[0][x] = (_Float16)(-L2E * aR[0][x]);   fR[0][4 + x] = (_Float16)(-L2E * aR[1][x]);
            fR[1][x] = (_Float16)(-L2E * aR[2][x]);   fR[1][4 + x] = (_Float16)(-L2E * aR[3][x]);
            fZ[0][x] = (_Float16)(-L2E * aZ[0][x]);   fZ[0][4 + x] = (_Float16)(-L2E * aZ[1][x]);
            fZ[1][x] = (_Float16)(-L2E * aZ[2][x]);   fZ[1][4 + x] = (_Float16)(-L2E * aZ[3][x]);
            fNi[0][x] = (_Float16)(2*L2E * aN[0][x]); fNi[0][4 + x] = (_Float16)(2*L2E * aN[1][x]);
            fNi[1][x] = (_Float16)(2*L2E * aN[2][x]); fNi[1][4 + x] = (_Float16)(2*L2E * aN[3][x]);
        }
        fR[2]  = ldw8s(wh + (u) * 64 + q * 8, -L2E);        fR[3]  = ldw8s(wh + (u) * 64 + 32 + q * 8, -L2E);
        fZ[2]  = ldw8s(wh + (64 + u) * 64 + q * 8, -L2E);   fZ[3]  = ldw8s(wh + (64 + u) * 64 + 32 + q * 8, -L2E);
        fNh[0] = ldw8s(wh + (128 + u) * 64 + q * 8, 2*L2E); fNh[1] = ldw8s(wh + (128 + u) * 64 + 32 + q * 8, 2*L2E);
        if (q == 0) {                                // fold-bias per hidden unit u (q-invariant)
            s_btmp[u] = bR; s_btmp[64 + u] = bZ; s_btmp[128 + u] = bN;
        }
        const int oc = (c < NOUTC) ? c : 0;
        fO[0] = ldw8s(out_w + oc * 64 + q * 8, 1.f);
        fO[1] = ldw8s(out_w + oc * 64 + 32 + q * 8, 1.f);
    } else {
        const float* wi = w_ih + l * 3 * HSZ * ESZ;
        const float* wh = w_hh + l * 3 * HSZ * ESZ;
        fR[0]  = ldw8s(wi + (u) * 64 + q * 8, -L2E);        fR[1]  = ldw8s(wi + (u) * 64 + 32 + q * 8, -L2E);
        fR[2]  = ldw8s(wh + (u) * 64 + q * 8, -L2E);        fR[3]  = ldw8s(wh + (u) * 64 + 32 + q * 8, -L2E);
        fZ[0]  = ldw8s(wi + (64 + u) * 64 + q * 8, -L2E);   fZ[1]  = ldw8s(wi + (64 + u) * 64 + 32 + q * 8, -L2E);
        fZ[2]  = ldw8s(wh + (64 + u) * 64 + q * 8, -L2E);   fZ[3]  = ldw8s(wh + (64 + u) * 64 + 32 + q * 8, -L2E);
        fNi[0] = ldw8s(wi + (128 + u) * 64 + q * 8, 2*L2E); fNi[1] = ldw8s(wi + (128 + u) * 64 + 32 + q * 8, 2*L2E);
        fNh[0] = ldw8s(wh + (128 + u) * 64 + q * 8, 2*L2E); fNh[1] = ldw8s(wh + (128 + u) * 64 + 32 + q * 8, 2*L2E);
    }
    __syncthreads();                                 // staging + s_btmp + flags visible

    // ---- per-lane bias vectors (C-init), hidden units u4..u4+3 ----
    floatx4 bR4, bZ4, bNi4, bNh4;
    if (l == 0) {
        #pragma unroll
        for (int i = 0; i < 4; ++i) {
            bR4[i]  = -L2E * (s_btmp[u4 + i] + b_ih[u4 + i] + b_hh[u4 + i]);
            bZ4[i]  = -L2E * (s_btmp[64 + u4 + i] + b_ih[64 + u4 + i] + b_hh[64 + u4 + i]);
            bNi4[i] = 2.f * L2E * (s_btmp[128 + u4 + i] + b_ih[128 + u4 + i]);
            bNh4[i] = 2.f * L2E * b_hh[128 + u4 + i];
        }
    } else {
        const int b0 = l * 192;
        floatx4 bi0 = *(const floatx4*)(b_ih + b0 + u4),       bh0 = *(const floatx4*)(b_hh + b0 + u4);
        floatx4 bi1 = *(const floatx4*)(b_ih + b0 + 64 + u4),  bh1 = *(const floatx4*)(b_hh + b0 + 64 + u4);
        floatx4 bi2 = *(const floatx4*)(b_ih + b0 + 128 + u4), bh2 = *(const floatx4*)(b_hh + b0 + 128 + u4);
        #pragma unroll
        for (int i = 0; i < 4; ++i) {
            bR4[i]  = -L2E * (bi0[i] + bh0[i]);
            bZ4[i]  = -L2E * (bi1[i] + bh1[i]);
            bNi4[i] = 2.f * L2E * bi2[i];
            bNh4[i] = 2.f * L2E * bh2[i];
        }
    }
    const float ob0 = out_b[0], ob1 = out_b[1];

    // ---- fp32 h-carry in VGPRs: carr[j][i] = h[u4+i][batch c] of tile j ----
    floatx4 ca0 = *(const floatx4*)(enc + (wgbase + 0 * 16 + c) * 64 + u4);
    floatx4 ca1 = *(const floatx4*)(enc + (wgbase + 1 * 16 + c) * 64 + u4);
    floatx4 ca2 = *(const floatx4*)(enc + (wgbase + 2 * 16 + c) * 64 + u4);
    floatx4 ca3 = *(const floatx4*)(enc + (wgbase + 3 * 16 + c) * 64 + u4);

    const int ar = c * LDW + (q << 3);               // act-frag elem offset (B-operand)
    const int fh = l * 4, fx = ((l == 0) ? 2 : (l - 1)) * 4;

    auto iter = [&](const int j, floatx4& carr, const int t) {
        const int parh = (t + 1) & 1, parw = t & 1;
        // wait: h_l(t-1) complete (all 4 col-groups)
        { volatile const int* f = &s_flag[fh + j]; const int tg = 4 * t; while (*f < tg) {} }
        asm volatile("" ::: "memory");
        const _Float16* hb = s_hl + ((fh + j) * 2 + parh) * TB;
        half8 ah0 = *(const half8*)(hb + ar), ah1 = *(const half8*)(hb + ar + 32);
        floatx4 accr = bR4, accz = bZ4, accni = bNi4, accnh = bNh4;
        accr  = MFMA(fR[2], ah0, accr);   accr  = MFMA(fR[3], ah1, accr);
        accz  = MFMA(fZ[2], ah0, accz);   accz  = MFMA(fZ[3], ah1, accz);
        accnh = MFMA(fNh[0], ah0, accnh); accnh = MFMA(fNh[1], ah1, accnh);
        // wait: x ready (l=0: h2(t-1) gen t; l>=1: h_{l-1}(t) gen t+1)
        { volatile const int* f = &s_flag[fx + j]; const int tg = (l == 0) ? 4 * t : 4 * t + 4; while (*f < tg) {} }
        asm volatile("" ::: "memory");
        const _Float16* xb = (l == 0) ? s_hl + ((2 * 4 + j) * 2 + parh) * TB
                                      : s_hl + (((l - 1) * 4 + j) * 2 + parw) * TB;
        half8 bx0 = *(const half8*)(xb + ar), bx1 = *(const half8*)(xb + ar + 32);
        if (l == 0 && g == 0 && t >= 1) {            // out(t-1) = h2(t-1) @ out_w.T + out_b
            floatx4 oa = {ob0, ob1, 0.f, 0.f};
            oa = MFMA(fO[0], bx0, oa);
            oa = MFMA(fO[1], bx1, oa);
            if (q == 0) {
                const long row = wgbase + j * 16 + c;
                *(floatx2*)(out + (row * TLEN + (t - 1)) * NOUTC) = floatx2{oa[0], oa[1]};
            }
        }
        accr  = MFMA(fR[0], bx0, accr);   accr  = MFMA(fR[1], bx1, accr);
        accz  = MFMA(fZ[0], bx0, accz);   accz  = MFMA(fZ[1], bx1, accz);
        accni = MFMA(fNi[0], bx0, accni); accni = MFMA(fNi[1], bx1, accni);
        half4 hv4; floatx4 hnew;
        #pragma unroll
        for (int i = 0; i < 4; ++i) {
            const float r  = __builtin_amdgcn_rcpf(1.f + __builtin_amdgcn_exp2f(accr[i]));
            const float z  = __builtin_amdgcn_rcpf(1.f + __builtin_amdgcn_exp2f(accz[i]));
            const float a  = accni[i] + r * accnh[i];
            const float n  = 1.f - 2.f * __builtin_amdgcn_rcpf(1.f + __builtin_amdgcn_exp2f(a));
            const float hv = n + z * (carr[i] - n);
            hnew[i] = hv; hv4[i] = (_Float16)hv;
        }
        *(half4*)(s_hl + ((fh + j) * 2 + parw) * TB + c * LDW + u4) = hv4;   // one b64 write
        carr = hnew;
        asm volatile("s_waitcnt lgkmcnt(0)" ::: "memory");                   // writes visible
        if (lane == 0) atomicAdd(&s_flag[fh + j], 1);                        // post gen t+1 (1/4)
    };

    for (int t = 0; t < TLEN; ++t) {
        iter(0, ca0, t); iter(1, ca1, t); iter(2, ca2, t); iter(3, ca3, t);
    }

    // ---- tail: out(127) from h2(127) ----
    if (l == 0 && g == 0) {
        #pragma unroll
        for (int j = 0; j < 4; ++j) {
            { volatile const int* f = &s_flag[2 * 4 + j]; while (*f < 4 * TLEN) {} }
            asm volatile("" ::: "memory");
            const _Float16* xb = s_hl + ((2 * 4 + j) * 2 + 1) * TB;          // parity 127&1 = 1
            half8 bx0 = *(const half8*)(xb + ar), bx1 = *(const half8*)(xb + ar + 32);
            floatx4 oa = {ob0, ob1, 0.f, 0.f};
            oa = MFMA(fO[0], bx0, oa);
            oa = MFMA(fO[1], bx1, oa);
            if (q == 0) {
                const long row = wgbase + j * 16 + c;
                *(floatx2*)(out + (row * TLEN + 127) * NOUTC) = floatx2{oa[0], oa[1]};
            }
        }
    }
}

extern "C" void kernel_launch(void* const* d_in, const int* in_sizes, int n_in,
                              void* d_out, int out_size, void* d_ws, size_t ws_size,
                              hipStream_t stream) {
    (void)in_sizes; (void)n_in; (void)d_ws; (void)ws_size; (void)out_size;
    const int grid = 16384 / 64;   // 256 workgroups, 1 per CU
    gru_pipe<<<grid, 768, 0, stream>>>(
        (const float*)d_in[0],  // agentFutureTrajEnc
        (const float*)d_in[1],  // emb_w
        (const float*)d_in[2],  // emb_b
        (const float*)d_in[3],  // w_ih
        (const float*)d_in[4],  // w_hh
        (const float*)d_in[5],  // b_ih
        (const float*)d_in[6],  // b_hh
        (const float*)d_in[7],  // out_w
        (const float*)d_in[8],  // out_b
        (float*)d_out);
}